// Round 7
// baseline (490.640 us; speedup 1.0000x reference)
//
#include <hip/hip_runtime.h>

// Transformer_67748814127473 — round 6: attn with 4-wave K/V tile sharing
// (L1-broadcast), j-half split + fp32 partials, combine+LN1 kernel.
// B=8, T=1024, N=2048, E=256, L=4.

#define BB 8
#define TT 1024
#define NN 2048
#define EE 256
#define LL 4

typedef __attribute__((ext_vector_type(8))) short short8;
typedef __attribute__((ext_vector_type(4))) float f32x4;

__device__ inline ushort f2b(float f) {
    union { float f; unsigned u; } x; x.f = f;
    unsigned u = x.u;
    return (ushort)((u + 0x7fffu + ((u >> 16) & 1u)) >> 16);
}
__device__ inline unsigned cvtpk(float lo, float hi) {
    unsigned r;
    asm volatile("v_cvt_pk_bf16_f32 %0, %1, %2" : "=v"(r) : "v"(lo), "v"(hi));
    return r;
}
// fragment-linear pack for K=256 operands: tile16(row) x kchunk32 -> [lane][8]
__device__ inline size_t pk256(int row, int k) {
    return ((size_t)((row >> 4) * 8 + (k >> 5))) * 512
         + (size_t)((((k >> 3) & 3) * 16 + (row & 15)) * 8 + (k & 7));
}
// V pack: (batch, token n, embed e) -> B-frag linear
__device__ inline size_t vpk_idx(int bb, int nn, int e) {
    return ((size_t)(bb*64 + (nn >> 5)) * 16 + (e >> 4)) * 512
         + (size_t)((((nn >> 3) & 3) * 16 + (e & 15)) * 8 + (nn & 7));
}

// ---------------- weight prep: transpose + cast + frag-pack ----------------
__global__ __launch_bounds__(256) void wprep_k(
    const float* __restrict__ Wq, const float* __restrict__ Wk,
    const float* __restrict__ Wv, const float* __restrict__ W1,
    const float* __restrict__ W2,
    ushort* __restrict__ WQKt, ushort* __restrict__ WVt,
    ushort* __restrict__ W1t, ushort* __restrict__ W2t)
{
    int id = blockIdx.x;          // 320 = 20 matrices x 16 tiles
    int m = id >> 4, t = id & 15;
    int l = m / 5, which = m % 5;
    const float* src; ushort* dst;
    size_t o = (size_t)l * 65536;
    switch (which) {
        case 0: src = Wq + o; dst = WQKt + (size_t)l*131072;          break;
        case 1: src = Wk + o; dst = WQKt + (size_t)l*131072 + 65536;  break;
        case 2: src = Wv + o; dst = WVt + o; break;
        case 3: src = W1 + o; dst = W1t + o; break;
        default: src = W2 + o; dst = W2t + o; break;
    }
    int tk = (t >> 2) * 64;   // k block
    int tn = (t & 3) * 64;    // n block (output col)
    __shared__ ushort T[64][68];
    int tid = threadIdx.x;
    int r = tid >> 4, c4 = (tid & 15) * 4;
    #pragma unroll
    for (int it = 0; it < 4; ++it) {
        int k = r + it*16;
        float4 v = *(const float4*)&src[(size_t)(tk + k)*256 + tn + c4];
        T[k][c4+0] = f2b(v.x); T[k][c4+1] = f2b(v.y);
        T[k][c4+2] = f2b(v.z); T[k][c4+3] = f2b(v.w);
    }
    __syncthreads();
    #pragma unroll
    for (int it = 0; it < 4; ++it) {
        int n = tn + r + it*16;
        int k0 = tk + c4;
        ushort4 ov;
        ov.x = T[c4+0][n-tn]; ov.y = T[c4+1][n-tn];
        ov.z = T[c4+2][n-tn]; ov.w = T[c4+3][n-tn];
        *(ushort4*)&dst[pk256(n, k0)] = ov;
    }
}

// ---------------- per-batch even-row base vector ----------------
__global__ __launch_bounds__(256) void base_even_k(
    const float* __restrict__ aset, const float* __restrict__ We,
    const float* __restrict__ be, float* __restrict__ BE)
{
    int b = blockIdx.x; int e = threadIdx.x;
    __shared__ float as[640];
    for (int i = e; i < 640; i += 256) as[i] = aset[b*640 + i];
    __syncthreads();
    float s = We[651*EE + e] + be[e];
    for (int f = 0; f < 640; ++f) s = fmaf(as[f], We[f*EE + e], s);
    BE[b*EE + e] = s;
}

// ---------------- embedding (8 rows per block), fp32 + packed bf16 ----------
__global__ __launch_bounds__(256) void embed_k(
    const float* __restrict__ BE, const float* __restrict__ ca,
    const float* __restrict__ cr, const float* __restrict__ We,
    const float* __restrict__ be, const float* __restrict__ wpe,
    float* __restrict__ H, ushort* __restrict__ Hbf)
{
    int e = threadIdx.x;
    #pragma unroll
    for (int k = 0; k < 8; ++k) {
        int rb = blockIdx.x * 8 + k;
        int b = rb >> 11, n = rb & (NN-1);
        float h;
        if ((n & 1) == 0) {
            h = BE[b*EE + e];
        } else {
            int t = n >> 1;
            h = We[651*EE + e] + be[e];
            const float* cap = ca + (size_t)(b*TT + t)*10;
            #pragma unroll
            for (int i = 0; i < 10; ++i) h = fmaf(cap[i], We[(640+i)*EE + e], h);
            h = fmaf(cr[b*TT + t], We[650*EE + e], h);
        }
        h = fmaf((float)(n + 1), We[652*EE + e], h);
        h += wpe[(size_t)n*EE + e];
        H[(size_t)rb*EE + e] = h;
        Hbf[pk256(rb, e)] = f2b(h);
    }
}

// ---------------- merged QKV GEMM (packed in, packed out) -------------------
__global__ __launch_bounds__(256, 2) void qkv_k(
    const ushort* __restrict__ A, const ushort* __restrict__ WQK,
    const ushort* __restrict__ WV,
    ushort* __restrict__ Qo, ushort* __restrict__ Ko, ushort* __restrict__ Vo)
{
    int tid = threadIdx.x;
    int w = tid >> 6, l = tid & 63;
    int lr = l & 15, lg = l >> 4;
    int wr = w >> 1, wc = w & 1;
    int rt0 = blockIdx.x * 8 + wr*4;
    int ct0 = blockIdx.y * 8 + wc*4;
    const ushort* Ap = A + (size_t)rt0*4096 + l*8;
    const ushort* Bp = (blockIdx.y < 4 ? WQK + (size_t)ct0*4096
                                       : WV + (size_t)(ct0-32)*4096) + l*8;
    f32x4 acc[4][4];
    #pragma unroll
    for (int i = 0; i < 4; ++i)
        #pragma unroll
        for (int j = 0; j < 4; ++j) acc[i][j] = (f32x4){0.f,0.f,0.f,0.f};
    #pragma unroll
    for (int kc = 0; kc < 8; ++kc) {
        short8 af[4], bf[4];
        #pragma unroll
        for (int rg = 0; rg < 4; ++rg) af[rg] = *(const short8*)(Ap + (size_t)rg*4096 + kc*512);
        #pragma unroll
        for (int cg = 0; cg < 4; ++cg) bf[cg] = *(const short8*)(Bp + (size_t)cg*4096 + kc*512);
        #pragma unroll
        for (int rg = 0; rg < 4; ++rg)
            #pragma unroll
            for (int cg = 0; cg < 4; ++cg)
                acc[rg][cg] = __builtin_amdgcn_mfma_f32_16x16x32_bf16(af[rg], bf[cg], acc[rg][cg], 0,0,0);
    }
    #pragma unroll
    for (int rg = 0; rg < 4; ++rg)
        #pragma unroll
        for (int cg = 0; cg < 4; ++cg)
            #pragma unroll
            for (int r = 0; r < 4; ++r) {
                int row = rt0*16 + rg*16 + lg*4 + r;
                int col = ct0*16 + cg*16 + lr;
                ushort xv = f2b(acc[rg][cg][r]);
                if (col < 256)      Qo[pk256(row, col)] = xv;
                else if (col < 512) Ko[pk256(row, col - 256)] = xv;
                else {
                    int e = col - 512, bb = row >> 11, nn = row & (NN-1);
                    Vo[vpk_idx(bb, nn, e)] = xv;
                }
            }
}

// ---------------- mlp1: relu(A@W1^T + b1) -> packed -------------------------
__global__ __launch_bounds__(256, 2) void mlp1_k(
    const ushort* __restrict__ A, const ushort* __restrict__ Bw,
    const float* __restrict__ bias, ushort* __restrict__ Cv)
{
    int tid = threadIdx.x;
    int w = tid >> 6, l = tid & 63;
    int lr = l & 15, lg = l >> 4;
    int wr = w >> 1, wc = w & 1;
    int rt0 = blockIdx.x * 8 + wr*4;
    int ct0 = blockIdx.y * 8 + wc*4;
    const ushort* Ap = A  + (size_t)rt0*4096 + l*8;
    const ushort* Bp = Bw + (size_t)ct0*4096 + l*8;
    f32x4 acc[4][4];
    #pragma unroll
    for (int i = 0; i < 4; ++i)
        #pragma unroll
        for (int j = 0; j < 4; ++j) acc[i][j] = (f32x4){0.f,0.f,0.f,0.f};
    #pragma unroll
    for (int kc = 0; kc < 8; ++kc) {
        short8 af[4], bf[4];
        #pragma unroll
        for (int rg = 0; rg < 4; ++rg) af[rg] = *(const short8*)(Ap + (size_t)rg*4096 + kc*512);
        #pragma unroll
        for (int cg = 0; cg < 4; ++cg) bf[cg] = *(const short8*)(Bp + (size_t)cg*4096 + kc*512);
        #pragma unroll
        for (int rg = 0; rg < 4; ++rg)
            #pragma unroll
            for (int cg = 0; cg < 4; ++cg)
                acc[rg][cg] = __builtin_amdgcn_mfma_f32_16x16x32_bf16(af[rg], bf[cg], acc[rg][cg], 0,0,0);
    }
    #pragma unroll
    for (int rg = 0; rg < 4; ++rg)
        #pragma unroll
        for (int cg = 0; cg < 4; ++cg)
            #pragma unroll
            for (int r = 0; r < 4; ++r) {
                int row = rt0*16 + rg*16 + lg*4 + r;
                int col = ct0*16 + cg*16 + lr;
                float x = fmaxf(acc[rg][cg][r] + bias[col], 0.f);
                Cv[pk256(row, col)] = f2b(x);
            }
}

// ---------------- mlp2 + residual + ln2 fused -------------------------------
__global__ __launch_bounds__(256, 2) void mlp2ln_k(
    const ushort* __restrict__ A, const ushort* __restrict__ Bw,
    const float* __restrict__ bias, const float* __restrict__ Res,
    const float* __restrict__ g, const float* __restrict__ bt,
    float* __restrict__ Hout, ushort* __restrict__ Hpk)
{
    int tid = threadIdx.x;
    int w = tid >> 6, l = tid & 63;
    int lr = l & 15, lg = l >> 4;
    int rt0 = blockIdx.x * 2;     // 32 rows
    int ct0 = w * 4;              // 64 cols per wave
    const ushort* Ap = A  + (size_t)rt0*4096 + l*8;
    const ushort* Bp = Bw + (size_t)ct0*4096 + l*8;
    f32x4 acc[2][4];
    #pragma unroll
    for (int i = 0; i < 2; ++i)
        #pragma unroll
        for (int j = 0; j < 4; ++j) acc[i][j] = (f32x4){0.f,0.f,0.f,0.f};
    #pragma unroll
    for (int kc = 0; kc < 8; ++kc) {
        short8 a0 = *(const short8*)(Ap + kc*512);
        short8 a1 = *(const short8*)(Ap + 4096 + kc*512);
        short8 bf[4];
        #pragma unroll
        for (int cg = 0; cg < 4; ++cg) bf[cg] = *(const short8*)(Bp + (size_t)cg*4096 + kc*512);
        #pragma unroll
        for (int cg = 0; cg < 4; ++cg) {
            acc[0][cg] = __builtin_amdgcn_mfma_f32_16x16x32_bf16(a0, bf[cg], acc[0][cg], 0,0,0);
            acc[1][cg] = __builtin_amdgcn_mfma_f32_16x16x32_bf16(a1, bf[cg], acc[1][cg], 0,0,0);
        }
    }
    __shared__ float red[32][4][2];
    float sm[2][4] = {}, sq[2][4] = {};
    #pragma unroll
    for (int rg = 0; rg < 2; ++rg)
        #pragma unroll
        for (int cg = 0; cg < 4; ++cg)
            #pragma unroll
            for (int r = 0; r < 4; ++r) {
                int grow = blockIdx.x*32 + rg*16 + lg*4 + r;
                int col = w*64 + cg*16 + lr;
                float v = acc[rg][cg][r] + bias[col] + Res[(size_t)grow*EE + col];
                acc[rg][cg][r] = v;
                sm[rg][r] += v; sq[rg][r] += v*v;
            }
    #pragma unroll
    for (int off = 1; off < 16; off <<= 1)
        #pragma unroll
        for (int rg = 0; rg < 2; ++rg)
            #pragma unroll
            for (int r = 0; r < 4; ++r) {
                sm[rg][r] += __shfl_xor(sm[rg][r], off);
                sq[rg][r] += __shfl_xor(sq[rg][r], off);
            }
    if (lr == 0) {
        #pragma unroll
        for (int rg = 0; rg < 2; ++rg)
            #pragma unroll
            for (int r = 0; r < 4; ++r) {
                int rl = rg*16 + lg*4 + r;
                red[rl][w][0] = sm[rg][r];
                red[rl][w][1] = sq[rg][r];
            }
    }
    __syncthreads();
    #pragma unroll
    for (int rg = 0; rg < 2; ++rg)
        #pragma unroll
        for (int r = 0; r < 4; ++r) {
            int rl = rg*16 + lg*4 + r;
            float S  = red[rl][0][0] + red[rl][1][0] + red[rl][2][0] + red[rl][3][0];
            float S2 = red[rl][0][1] + red[rl][1][1] + red[rl][2][1] + red[rl][3][1];
            float mean = S * (1.0f/256.0f);
            float var  = S2 * (1.0f/256.0f) - mean*mean;
            float inv  = 1.0f / sqrtf(var + 1e-5f);
            int grow = blockIdx.x*32 + rl;
            #pragma unroll
            for (int cg = 0; cg < 4; ++cg) {
                int col = w*64 + cg*16 + lr;
                float y = (acc[rg][cg][r] - mean) * inv * g[col] + bt[col];
                Hout[(size_t)grow*EE + col] = y;
                Hpk[pk256(grow, col)] = f2b(y);
            }
        }
}

// ---------------- causal relu-attention, 4-wave tile-share, j-halves --------
// Block = (batch b, 64-row slice p, j-half h). 4 waves, wave w owns rows
// p*64+16w..+15; all 4 waves process the SAME jt each iteration (identical
// K/V fragment addresses -> L1 broadcast), barrier-locked per iter.
// Writes partial O (fp32) to Oa (h=0) / Ob (h=1); epilogue in comb_ln1_k.
__global__ __launch_bounds__(256, 2) void attn_k(
    const ushort* __restrict__ Qp, const ushort* __restrict__ Kp,
    const ushort* __restrict__ Vp, float* __restrict__ Oa,
    float* __restrict__ Ob)
{
    int bi = blockIdx.x;             // 0..511
    int h = bi >> 8;
    int j = bi & 255;
    int b = j >> 5;
    int p = h ? (31 - (j & 31)) : (j & 31);   // complementary sizes pair on CU
    int tid = threadIdx.x;
    int w = tid >> 6, l = tid & 63;
    int lr = l & 15, lg = l >> 4;
    int i0 = p*64 + w*16;            // wave's Q rows (local to batch)
    int j0 = h ? (p + 1) : 0;
    int j1 = h ? (2*p + 2) : (p + 1);
    float* Op = h ? Ob : Oa;

    const ushort* Qt    = Qp + (size_t)(b*128 + p*4 + w)*4096 + l*8;
    const ushort* Kbase = Kp + (size_t)(b*128)*4096 + l*8;
    const ushort* Vbase = Vp + (size_t)(b*64)*16*512 + l*8;

    short8 qb[8];
    #pragma unroll
    for (int kc = 0; kc < 8; ++kc) qb[kc] = *(const short8*)(Qt + kc*512);

    f32x4 oacc[16];
    #pragma unroll
    for (int et = 0; et < 16; ++et) oacc[et] = (f32x4){0.f,0.f,0.f,0.f};

    int ig = i0 + lr;
    for (int jt = j0; jt < j1; ++jt) {
        // identical addresses across all 4 waves -> L1-shared
        const ushort* Kt = Kbase + (size_t)(jt*2) * 4096;
        short8 ka0[8], ka1[8];
        #pragma unroll
        for (int kc = 0; kc < 8; ++kc) {
            ka0[kc] = *(const short8*)(Kt + kc*512);
            ka1[kc] = *(const short8*)(Kt + 4096 + kc*512);
        }
        const ushort* Vt = Vbase + (size_t)(jt*16) * 512;
        short8 vf[16];
        #pragma unroll
        for (int et = 0; et < 16; ++et)
            vf[et] = *(const short8*)(Vt + et*512);
        // QK^T (swapped), 4 independent chains
        f32x4 c0a = {0.f,0.f,0.f,0.f}, c0b = {0.f,0.f,0.f,0.f};
        f32x4 c1a = {0.f,0.f,0.f,0.f}, c1b = {0.f,0.f,0.f,0.f};
        #pragma unroll
        for (int kc = 0; kc < 8; kc += 2) {
            c0a = __builtin_amdgcn_mfma_f32_16x16x32_bf16(ka0[kc],   qb[kc],   c0a, 0,0,0);
            c0b = __builtin_amdgcn_mfma_f32_16x16x32_bf16(ka0[kc+1], qb[kc+1], c0b, 0,0,0);
            c1a = __builtin_amdgcn_mfma_f32_16x16x32_bf16(ka1[kc],   qb[kc],   c1a, 0,0,0);
            c1b = __builtin_amdgcn_mfma_f32_16x16x32_bf16(ka1[kc+1], qb[kc+1], c1b, 0,0,0);
        }
        f32x4 c0 = c0a + c0b, c1 = c1a + c1b;
        // relu + causal mask (j <= i)
        #pragma unroll
        for (int r = 0; r < 4; ++r) {
            int jg = jt*32 + lg*4 + r;
            c0[r] = (jg <= ig) ? fmaxf(c0[r], 0.f) : 0.f;
            c1[r] = (jg + 16 <= ig) ? fmaxf(c1[r], 0.f) : 0.f;
        }
        // pack to bf16 pairs, repack C-layout -> PV A-frag via shfl
        unsigned u0 = cvtpk(c0[0], c0[1]), u1 = cvtpk(c0[2], c0[3]);
        unsigned u2 = cvtpk(c1[0], c1[1]), u3 = cvtpk(c1[2], c1[3]);
        int srcA = 32*(lg & 1) + lr;
        int srcB = srcA + 16;
        unsigned a0A = __shfl((int)u0, srcA), a1A = __shfl((int)u1, srcA);
        unsigned a0B = __shfl((int)u0, srcB), a1B = __shfl((int)u1, srcB);
        unsigned b0A = __shfl((int)u2, srcA), b1A = __shfl((int)u3, srcA);
        unsigned b0B = __shfl((int)u2, srcB), b1B = __shfl((int)u3, srcB);
        bool lo = (lg < 2);
        union { unsigned u[4]; short8 v; } sv;
        sv.u[0] = lo ? a0A : b0A;
        sv.u[1] = lo ? a1A : b1A;
        sv.u[2] = lo ? a0B : b0B;
        sv.u[3] = lo ? a1B : b1B;
        short8 sa = sv.v;
        // PV: O[16][256] += S @ V_jt
        __builtin_amdgcn_s_setprio(1);
        #pragma unroll
        for (int et = 0; et < 16; ++et)
            oacc[et] = __builtin_amdgcn_mfma_f32_16x16x32_bf16(sa, vf[et], oacc[et], 0,0,0);
        __builtin_amdgcn_s_setprio(0);
        __syncthreads();   // keep 4 waves on same jt for L1 locality
    }
    // write partial O (fp32)
    #pragma unroll
    for (int et = 0; et < 16; ++et)
        #pragma unroll
        for (int r = 0; r < 4; ++r) {
            int irow = i0 + lg*4 + r;
            Op[((size_t)(b*NN + irow))*EE + et*16 + lr] = oacc[et][r];
        }
}

// ---------------- combine partials + residual + scale + LN1 -----------------
// 1 wave per row. x = H + (Oa+Ob)/(i+1); y = LN1(x) -> Xout fp32 + packed.
// NOTE: Oa may alias Xout (per-thread read-before-write, disjoint elements).
__global__ __launch_bounds__(256) void comb_ln1_k(
    const float* Oa, const float* __restrict__ Ob,
    const float* __restrict__ H, const float* __restrict__ g,
    const float* __restrict__ bt, float* Xout, ushort* __restrict__ Lpk)
{
    int w = threadIdx.x >> 6, l = threadIdx.x & 63;
    size_t row = (size_t)blockIdx.x*4 + w;
    float sc = 1.0f / (float)((row & (NN-1)) + 1);
    float4 oa = *(const float4*)&Oa[row*EE + l*4];
    float4 ob = *(const float4*)&Ob[row*EE + l*4];
    float4 hh = *(const float4*)&H[row*EE + l*4];
    float4 x;
    x.x = hh.x + (oa.x + ob.x)*sc;
    x.y = hh.y + (oa.y + ob.y)*sc;
    x.z = hh.z + (oa.z + ob.z)*sc;
    x.w = hh.w + (oa.w + ob.w)*sc;
    float s  = x.x + x.y + x.z + x.w;
    float s2 = x.x*x.x + x.y*x.y + x.z*x.z + x.w*x.w;
    #pragma unroll
    for (int off = 1; off < 64; off <<= 1) {
        s  += __shfl_xor(s,  off);
        s2 += __shfl_xor(s2, off);
    }
    float mean = s * (1.0f/256.0f);
    float var  = s2 * (1.0f/256.0f) - mean*mean;
    float inv  = 1.0f / sqrtf(var + 1e-5f);
    float4 gv = *(const float4*)&g[l*4];
    float4 bv = *(const float4*)&bt[l*4];
    float4 y;
    y.x = (x.x - mean)*inv*gv.x + bv.x;
    y.y = (x.y - mean)*inv*gv.y + bv.y;
    y.z = (x.z - mean)*inv*gv.z + bv.z;
    y.w = (x.w - mean)*inv*gv.w + bv.w;
    *(float4*)&Xout[row*EE + l*4] = y;
    ushort4 yb; yb.x = f2b(y.x); yb.y = f2b(y.y); yb.z = f2b(y.z); yb.w = f2b(y.w);
    *(ushort4*)&Lpk[pk256((int)row, l*4)] = yb;
}

// ---------------- prediction head (even rows only) ----------------
__global__ __launch_bounds__(256) void pred_k(
    const float* __restrict__ H, const float* __restrict__ Wp,
    const float* __restrict__ bp, float* __restrict__ out)
{
    int bt = blockIdx.x;
    int b = bt >> 10, t = bt & 1023;
    size_t row = (size_t)b*NN + 2*t;
    __shared__ float hs[256];
    __shared__ float pr[16][16];
    int tid = threadIdx.x;
    hs[tid] = H[row*EE + tid];
    __syncthreads();
    int c = tid & 15, seg = tid >> 4;
    float p = 0.f;
    if (c < 10) {
        #pragma unroll
        for (int e2 = 0; e2 < 16; ++e2)
            p = fmaf(hs[seg*16 + e2], Wp[(seg*16 + e2)*10 + c], p);
    }
    pr[seg][c] = p;
    __syncthreads();
    if (tid < 10) {
        float sacc = bp[tid];
        #pragma unroll
        for (int k2 = 0; k2 < 16; ++k2) sacc += pr[k2][tid];
        out[(size_t)bt*10 + tid] = sacc;
    }
}

extern "C" void kernel_launch(void* const* d_in, const int* in_sizes, int n_in,
                              void* d_out, int out_size, void* d_ws, size_t ws_size,
                              hipStream_t stream)
{
    const float* action_set = (const float*)d_in[1];
    const float* ctx_act    = (const float*)d_in[2];
    const float* ctx_rew    = (const float*)d_in[3];
    const float* W_embed    = (const float*)d_in[4];
    const float* b_embed    = (const float*)d_in[5];
    const float* wpe        = (const float*)d_in[6];
    const float* Wq         = (const float*)d_in[7];
    const float* Wk         = (const float*)d_in[8];
    const float* Wv         = (const float*)d_in[9];
    const float* ln1g       = (const float*)d_in[10];
    const float* ln1b       = (const float*)d_in[11];
    const float* W1         = (const float*)d_in[12];
    const float* b1         = (const float*)d_in[13];
    const float* W2         = (const float*)d_in[14];
    const float* b2         = (const float*)d_in[15];
    const float* ln2g       = (const float*)d_in[16];
    const float* ln2b       = (const float*)d_in[17];
    const float* Wp         = (const float*)d_in[18];
    const float* bp         = (const float*)d_in[19];
    float* out = (float*)d_out;

    float* ws = (float*)d_ws;
    const size_t SZ = (size_t)BB*NN*EE;   // 4,194,304
    size_t o = 0;
    float*  Hb   = ws;               o += SZ;        // fp32 residual stream
    float*  Xb   = ws + o;           o += SZ;        // Oa partial / ln1 fp32 out
    float*  Obuf = ws + o;           o += SZ;        // Ob partial
    ushort* Hbf  = (ushort*)(ws+o);  o += SZ/2;      // packed bf16 stream / ln1-packed
    ushort* Qp   = (ushort*)(ws+o);  o += SZ/2;      // packed Q; aliased MLP-mid
    ushort* Kpk  = (ushort*)(ws+o);  o += SZ/2;      // packed K
    ushort* Vpk  = (ushort*)(ws+o);  o += SZ/2;      // packed V
    ushort* WQKt = (ushort*)(ws+o);  o += 262144;
    ushort* WVt  = (ushort*)(ws+o);  o += 131072;
    ushort* W1t  = (ushort*)(ws+o);  o += 131072;
    ushort* W2t  = (ushort*)(ws+o);  o += 131072;
    float*  BE   = ws + o;

    wprep_k<<<320, 256, 0, stream>>>(Wq, Wk, Wv, W1, W2, WQKt, WVt, W1t, W2t);
    base_even_k<<<BB, 256, 0, stream>>>(action_set, W_embed, b_embed, BE);
    embed_k<<<BB*NN/8, 256, 0, stream>>>(BE, ctx_act, ctx_rew, W_embed, b_embed, wpe, Hb, Hbf);

    for (int l = 0; l < LL; ++l) {
        qkv_k<<<dim3(128, 6), 256, 0, stream>>>(
            Hbf, WQKt + (size_t)l*131072, WVt + (size_t)l*65536, Qp, Kpk, Vpk);
        // attention partials: Oa -> Xb, Ob -> Obuf
        attn_k<<<512, 256, 0, stream>>>(Qp, Kpk, Vpk, Xb, Obuf);
        // combine + residual + ln1 -> Xb (fp32) + Hbf (packed; dead, safe)
        comb_ln1_k<<<BB*NN/4, 256, 0, stream>>>(
            Xb, Obuf, Hb, ln1g + l*EE, ln1b + l*EE, Xb, Hbf);
        // mlp1: relu(ln1 @ W1 + b1) -> Qp (packed mid)
        mlp1_k<<<dim3(128, 2), 256, 0, stream>>>(
            Hbf, W1t + (size_t)l*65536, b1 + l*EE, Qp);
        // mlp2 + residual(Xb) + ln2 -> Hb (fp32) + Hbf (packed stream)
        mlp2ln_k<<<512, 256, 0, stream>>>(
            Qp, W2t + (size_t)l*65536, b2 + l*EE, Xb,
            ln2g + l*EE, ln2b + l*EE, Hb, Hbf);
    }
    pred_k<<<BB*TT, 256, 0, stream>>>(Hb, Wp, bp, out);
}